// Round 1
// 80.132 us; speedup vs baseline: 1.0846x; 1.0846x over previous
//
#include <hip/hip_runtime.h>
#include <stdint.h>

#define N 8192
#define MAX_E (64 * N)          // 524288
#define NCHUNK (N / 64)         // 128 mask chunks per row
#define NCOL1 9                 // 9x9x9 grid, width 50/9 = 5.556 > 5 + eps
#define NCELLS (NCOL1 * NCOL1 * NCOL1)   // 729 cells (3D now: z is binned too)
#define SCALE (9.0f / 50.0f)
#define POISON 0xAAAAAAAAu      // harness poisons d_ws to 0xAA before EVERY launch
#define M_WAVES 4               // rows per mask block (1 row per wave)
#define E_BLOCKS 512            // emit blocks (16 rows each)
#define E_ROWS 16

// Exact replication of numpy f32: sum(pos*pos, -1) = ((x*x)+(y*y))+(z*z),
// each product rounded (no fma).
__device__ __forceinline__ float sq_exact(float x, float y, float z) {
    return __fadd_rn(__fadd_rn(__fmul_rn(x, x), __fmul_rn(y, y)), __fmul_rn(z, z));
}

// d2 = RN(sqsum - RN(2*dot)); 2*dot is exact so fma(-2,dot,sqsum) is bit-identical.
// dist<5 <=> d2 < 0x1.8ffffep+4f (largest f32 below 25 has correctly-rounded sqrt
// equal to exactly 5.0, so that value must be excluded).
// |computed d2 - true d^2| <= ~7e-3, so pairs whose cells differ by >=2 in ANY
// coordinate (now including z) have computed d2 > 30.8 >> threshold -> provably
// non-edges; the 3x3x3 neighbor-cell filter is bit-exact.
__device__ __forceinline__ bool edge_pred(float xi, float yi, float zi, float sqi,
                                          const float4& pj) {
    float dot = __fmaf_rn(zi, pj.z, __fmaf_rn(yi, pj.y, __fmul_rn(xi, pj.x)));
    float d2  = __fmaf_rn(-2.0f, dot, __fadd_rn(sqi, pj.w));
    return d2 < 0x1.8ffffep+4f;
}

__device__ __forceinline__ int cell_of(float v) {
    int c = (int)(__fmul_rn(v, SCALE));
    return c > 8 ? 8 : c;       // v=49.99999 -> product can round to 9.0
}

__device__ __forceinline__ int cell3_of(float x, float y, float z) {
    return (cell_of(x) * NCOL1 + cell_of(y)) * NCOL1 + cell_of(z);
}

// Pass A: count points per 3D cell. 8192 atomics over 729 counters (~11/cell,
// vs the old 101-deep contention on 81 2D counters). Counts ride on the 0xAA
// poison base (documented harness contract); scan subtracts it.
__global__ __launch_bounds__(256) void count_kernel(const float* __restrict__ posf,
                                                    unsigned* __restrict__ gcount) {
    const int i = blockIdx.x * 256 + threadIdx.x;   // grid = 32 blocks
    float x = posf[3 * i], y = posf[3 * i + 1], z = posf[3 * i + 2];
    atomicAdd(&gcount[cell3_of(x, y, z)], 1u);
}

// Pass B: single-block exclusive scan of the 729 counts -> cbase[730] and the
// scatter cursors (cursor[c] starts at cbase[c]; atomicAdd yields the absolute
// compact slot). Compaction => column z-cells are CONTIGUOUS in memory and all
// 8192 slots are written: no CAP, no overflow risk, no poisoned reads ever.
__global__ __launch_bounds__(256) void scan_kernel(const unsigned* __restrict__ gcount,
                                                   int* __restrict__ cbase,
                                                   int* __restrict__ cursor) {
    __shared__ int part[256];
    const int tid = threadIdx.x;
    const int i0 = tid * 3;
    int c0 = (i0 + 0 < NCELLS) ? (int)(gcount[i0 + 0] - POISON) : 0;
    int c1 = (i0 + 1 < NCELLS) ? (int)(gcount[i0 + 1] - POISON) : 0;
    int c2 = (i0 + 2 < NCELLS) ? (int)(gcount[i0 + 2] - POISON) : 0;
    const int s = c0 + c1 + c2;
    part[tid] = s;
    __syncthreads();
    for (int off = 1; off < 256; off <<= 1) {
        int v = (tid >= off) ? part[tid - off] : 0;
        __syncthreads();
        part[tid] += v;
        __syncthreads();
    }
    int run = part[tid] - s;                        // exclusive prefix
    if (i0 + 0 < NCELLS) { cbase[i0 + 0] = run; cursor[i0 + 0] = run; run += c0; }
    if (i0 + 1 < NCELLS) { cbase[i0 + 1] = run; cursor[i0 + 1] = run; run += c1; }
    if (i0 + 2 < NCELLS) { cbase[i0 + 2] = run; cursor[i0 + 2] = run; run += c2; }
    if (tid == 255) cbase[NCELLS] = part[255];      // = N = 8192 exactly
}

// Pass C: scatter points into the compact cell layout. Slot order within a
// cell is nondeterministic -> irrelevant (masks are positional bits).
// NO fences (R8 lesson); inter-kernel visibility guaranteed by stream order.
__global__ __launch_bounds__(256) void scatter_kernel(const float* __restrict__ posf,
                                                      int* __restrict__ cursor,
                                                      float4* __restrict__ colpts,
                                                      int* __restrict__ colidx) {
    const int i = blockIdx.x * 256 + threadIdx.x;   // grid = 32 blocks
    float x = posf[3 * i], y = posf[3 * i + 1], z = posf[3 * i + 2];
    const int slot = atomicAdd(&cursor[cell3_of(x, y, z)], 1);
    colpts[slot] = make_float4(x, y, z, sq_exact(x, y, z));
    colidx[slot] = i;
}

// Pass 1: one wave per row. With 3D binning + compaction, each row scans 9
// CONTIGUOUS ranges (z-window [cz-1,cz+1] of each neighbor column), ~306 avg
// candidates vs ~910 with 2D bins: ~2.1M evals, ~9 batches/row vs ~15.
__global__ __launch_bounds__(256) void mask_kernel(const float* __restrict__ posf,
                                                   const int* __restrict__ cbase,
                                                   const float4* __restrict__ colpts,
                                                   const int* __restrict__ colidx,
                                                   uint64_t* __restrict__ masks,
                                                   int* __restrict__ counts) {
    __shared__ uint32_t lmask[M_WAVES][256];   // 1KB bitmap per row
    const int tid  = threadIdx.x;
    const int wave = tid >> 6;
    const int lane = tid & 63;
    const int row  = blockIdx.x * M_WAVES + wave;

#pragma unroll
    for (int k = lane; k < 256; k += 64) lmask[wave][k] = 0;

    const float xi = posf[3 * row], yi = posf[3 * row + 1], zi = posf[3 * row + 2];
    const float sqi = sq_exact(xi, yi, zi);
    const int cx = cell_of(xi), cy = cell_of(yi), cz = cell_of(zi);
    const int zlo = (cz > 0) ? cz - 1 : 0;
    const int zhi = (cz < 8) ? cz + 1 : 8;
    __syncthreads();

    // Prefetch all 9 range descriptors up front (fully unrolled -> registers,
    // no scratch; invalid neighbor columns collapse to zero-length ranges).
    int starts[9], ends[9];
#pragma unroll
    for (int q = 0; q < 9; q++) {
        const int nx = cx + q / 3 - 1;
        const int ny = cy + q % 3 - 1;
        const bool v = ((unsigned)nx <= 8u) & ((unsigned)ny <= 8u);
        const int col = v ? nx * NCOL1 + ny : 0;
        const int s0 = cbase[col * NCOL1 + zlo];
        const int e0 = cbase[col * NCOL1 + zhi + 1];
        starts[q] = s0;
        ends[q]   = v ? e0 : s0;
    }

#pragma unroll
    for (int q = 0; q < 9; q++) {
        for (int k = starts[q] + lane; k < ends[q]; k += 64) {
            float4 pj = colpts[k];
            int j = colidx[k];
            if (j != row && edge_pred(xi, yi, zi, sqi, pj))
                atomicOr(&lmask[wave][j >> 5], 1u << (j & 31));
        }
    }
    __syncthreads();

    // readback: lane l holds words 4l..4l+3 = chunks 2l, 2l+1
    uint4 u = ((const uint4*)lmask[wave])[lane];
    uint64_t k0 = (uint64_t)u.x | ((uint64_t)u.y << 32);
    uint64_t k1 = (uint64_t)u.z | ((uint64_t)u.w << 32);
    ulonglong2 v; v.x = k0; v.y = k1;
    ((ulonglong2*)(masks + (size_t)row * NCHUNK))[lane] = v;
    int t = __popcll(k0) + __popcll(k1);
#pragma unroll
    for (int o = 32; o > 0; o >>= 1) t += __shfl_down(t, o);
    if (lane == 0) counts[row] = t;
}

// Pass 2: masks -> ordered edge list + tail fill with -1. Each block
// redundantly recomputes the row-offset scan from counts (32KB, L2-hot;
// no inter-block comms, no fence).
__global__ __launch_bounds__(256) void emit_kernel(const uint64_t* __restrict__ masks,
                                                   const int* __restrict__ counts,
                                                   int* __restrict__ out) {
    const int tid  = threadIdx.x;
    const int wave = tid >> 6;
    const int lane = tid & 63;
    const int row0 = blockIdx.x * E_ROWS;

    __shared__ int part[256];
    __shared__ int excl32[32];

    // thread t sums rows [t*32, t*32+32)
    const int4* c4 = (const int4*)counts;
    int s = 0;
#pragma unroll
    for (int k = 0; k < 8; k++) {
        int4 v = c4[tid * 8 + k];
        s += v.x + v.y + v.z + v.w;
    }
    part[tid] = s;
    const int ch = row0 >> 5;                  // this block's 32-row chunk
    if (tid < 32) excl32[tid] = counts[(ch << 5) + tid];
    __syncthreads();
    for (int off = 1; off < 256; off <<= 1) {
        int v = (tid >= off) ? part[tid - off] : 0;
        __syncthreads();
        part[tid] += v;
        __syncthreads();
    }
    if (tid == 0) {                            // tiny LDS-local 32-scan
        int run = 0;
#pragma unroll
        for (int k = 0; k < 32; k++) { int c = excl32[k]; excl32[k] = run; run += c; }
    }
    __syncthreads();
    const int base = (ch > 0) ? part[ch - 1] : 0;
    const int E    = part[255];
    const int sub  = row0 & 31;                // 0 or 16

    // tail fill: slots [E, MAX_E) of both halves get -1
    for (int idx = E + blockIdx.x * 256 + tid; idx < MAX_E; idx += E_BLOCKS * 256) {
        out[idx] = -1; out[MAX_E + idx] = -1;
    }

#pragma unroll
    for (int r = 0; r < 4; r++) {
        const int lr  = wave * 4 + r;          // 0..15
        const int row = row0 + lr;
        ulonglong2 v = ((const ulonglong2*)(masks + (size_t)row * NCHUNK))[lane];
        int s0 = __popcll(v.x), s1 = __popcll(v.y);
        int x = s0 + s1;
#pragma unroll
        for (int o = 1; o < 64; o <<= 1) {
            int t = __shfl_up(x, o);
            if (lane >= o) x += t;
        }
        int slot = base + excl32[sub + lr] + (x - (s0 + s1));

        const int col0 = lane * 128;
        uint64_t m = v.x;
        while (m) {
            int b = __ffsll((unsigned long long)m) - 1;
            m &= m - 1;
            if (slot < MAX_E) { out[slot] = row; out[MAX_E + slot] = col0 + b; }
            slot++;
        }
        m = v.y;
        while (m) {
            int b = __ffsll((unsigned long long)m) - 1;
            m &= m - 1;
            if (slot < MAX_E) { out[slot] = row; out[MAX_E + slot] = col0 + 64 + b; }
            slot++;
        }
    }
}

extern "C" void kernel_launch(void* const* d_in, const int* in_sizes, int n_in,
                              void* d_out, int out_size, void* d_ws, size_t ws_size,
                              hipStream_t stream) {
    const float* posf = (const float*)d_in[0];
    int* out = (int*)d_out;
    char* ws = (char*)d_ws;
    int*      counts = (int*)ws;                        // 32KB @ 0
    unsigned* gcount = (unsigned*)(ws + (64 << 10));    // 729 uints @ 64KB (poisoned)
    int*      cbase  = (int*)(ws + (72 << 10));         // 730 ints @ 72KB
    int*      cursor = (int*)(ws + (80 << 10));         // 729 ints @ 80KB
    int*      colidx = (int*)(ws + (128 << 10));        // 8192 ints = 32KB @ 128KB
    float4*   colpts = (float4*)(ws + (192 << 10));     // 8192 float4 = 128KB @ 192KB
    uint64_t* masks  = (uint64_t*)(ws + (1 << 20));     // 8MB @ 1MB

    count_kernel<<<N / 256, 256, 0, stream>>>(posf, gcount);
    scan_kernel<<<1, 256, 0, stream>>>(gcount, cbase, cursor);
    scatter_kernel<<<N / 256, 256, 0, stream>>>(posf, cursor, colpts, colidx);
    mask_kernel<<<N / M_WAVES, 256, 0, stream>>>(posf, cbase, colpts, colidx,
                                                 masks, counts);
    emit_kernel<<<E_BLOCKS, 256, 0, stream>>>(masks, counts, out);
}